// Round 10
// baseline (319.275 us; speedup 1.0000x reference)
//
#include <hip/hip_runtime.h>

#define NZ 81
#define OBS_DIM 48
#define MAX_ADJ 5
#define NTASK (NZ * MAX_ADJ)   // 405
#define TPAD 408
#define NEG_INF -1000000000.0f
#define BLOCK 512
#define ROWS 16                // batch rows per block
#define CHUNK 4                // rows per compute chunk
#define NCHUNK (ROWS / CHUNK)  // 4
#define ROW_DW (NZ * NZ)       // 6561
#define NPOS 13                // ceil(6561/512)

__global__ __launch_bounds__(BLOCK) void taxi_actor_kernel(
    const float* __restrict__ obs,   // [B, 48]
    const float* __restrict__ W,     // [81, 48, 5]
    const float* __restrict__ bias,  // [81, 5]
    const int*   __restrict__ idx,   // [81, 5]
    const float* __restrict__ mask,  // [81, 5]
    float* __restrict__ out)         // [B, 81, 81]
{
    __shared__ float s_obs[ROWS * OBS_DIM];     // 3 KB
    __shared__ float s_lp[2][CHUNK][TPAD];      // 13 KB, double-buffered probs
    __shared__ int   s_idx[NTASK];              // 1.6 KB (masked -> -1)
    __shared__ short s_map[ROW_DW + 7];         // 13.1 KB: dword pos -> task (-1 = zero)

    const int tid = threadIdx.x;
    const size_t b0 = (size_t)blockIdx.x * ROWS;

    // Stage obs rows (vectorized, coalesced) + adjacency.
    if (tid < ROWS * OBS_DIM / 4) {
        const float4* src = reinterpret_cast<const float4*>(obs + b0 * OBS_DIM);
        reinterpret_cast<float4*>(s_obs)[tid] = src[tid];
    }
    if (tid < NTASK)
        s_idx[tid] = (mask[tid] > 0.0f) ? idx[tid] : -1;
    __syncthreads();

    // Position -> task map in LDS (no registers held across phases).
    for (int p = tid; p < ROW_DW; p += BLOCK) {
        const int n = p / NZ;
        const int z = p - n * NZ;
        short t = -1;
        #pragma unroll
        for (int k = 0; k < MAX_ADJ; ++k)
            if (s_idx[n * MAX_ADJ + k] == z) t = (short)(n * MAX_ADJ + k);
        s_map[p] = t;
    }

    // Per-task constants.
    const float* __restrict__ Wp = W;
    float bv = 0.0f;
    bool valid = false;
    if (tid < NTASK) {
        const int n = tid / MAX_ADJ;
        const int k = tid - n * MAX_ADJ;
        Wp = W + n * (OBS_DIM * MAX_ADJ) + k;
        bv = bias[tid];
        valid = (mask[tid] > 0.0f);
    }

    // Chunk compute: 4-row batched dot, W element loaded once -> 4 FMAs.
    auto compute_chunk = [&](int c) {
        if (tid < NTASK) {
            const int rb = c * CHUNK;
            const int buf = c & 1;
            float a0 = 0.f, a1 = 0.f, a2 = 0.f, a3 = 0.f;
            #pragma unroll
            for (int d4 = 0; d4 < OBS_DIM; d4 += 4) {
                const float w0 = Wp[(d4 + 0) * MAX_ADJ];
                const float w1 = Wp[(d4 + 1) * MAX_ADJ];
                const float w2 = Wp[(d4 + 2) * MAX_ADJ];
                const float w3 = Wp[(d4 + 3) * MAX_ADJ];
                const float4 o0 = *reinterpret_cast<const float4*>(&s_obs[(rb + 0) * OBS_DIM + d4]);
                const float4 o1 = *reinterpret_cast<const float4*>(&s_obs[(rb + 1) * OBS_DIM + d4]);
                const float4 o2 = *reinterpret_cast<const float4*>(&s_obs[(rb + 2) * OBS_DIM + d4]);
                const float4 o3 = *reinterpret_cast<const float4*>(&s_obs[(rb + 3) * OBS_DIM + d4]);
                a0 = fmaf(o0.x, w0, a0); a0 = fmaf(o0.y, w1, a0); a0 = fmaf(o0.z, w2, a0); a0 = fmaf(o0.w, w3, a0);
                a1 = fmaf(o1.x, w0, a1); a1 = fmaf(o1.y, w1, a1); a1 = fmaf(o1.z, w2, a1); a1 = fmaf(o1.w, w3, a1);
                a2 = fmaf(o2.x, w0, a2); a2 = fmaf(o2.y, w1, a2); a2 = fmaf(o2.z, w2, a2); a2 = fmaf(o2.w, w3, a2);
                a3 = fmaf(o3.x, w0, a3); a3 = fmaf(o3.y, w1, a3); a3 = fmaf(o3.z, w2, a3); a3 = fmaf(o3.w, w3, a3);
            }
            s_lp[buf][0][tid] = valid ? (a0 + bv) : NEG_INF;
            s_lp[buf][1][tid] = valid ? (a1 + bv) : NEG_INF;
            s_lp[buf][2][tid] = valid ? (a2 + bv) : NEG_INF;
            s_lp[buf][3][tid] = valid ? (a3 + bv) : NEG_INF;
        }
    };

    auto softmax_chunk = [&](int c) {
        if (tid < CHUNK * NZ) {               // 324 tasks
            const int buf = c & 1;
            const int r = tid / NZ;
            const int n = tid - r * NZ;
            float l[MAX_ADJ];
            float m = NEG_INF;
            #pragma unroll
            for (int k = 0; k < MAX_ADJ; ++k) {
                l[k] = s_lp[buf][r][n * MAX_ADJ + k];
                m = fmaxf(m, l[k]);
            }
            float ssum = 0.0f;
            #pragma unroll
            for (int k = 0; k < MAX_ADJ; ++k) {
                l[k] = __expf(l[k] - m);      // masked: exp(-1e9) -> 0
                ssum += l[k];
            }
            const float inv = 1.0f / ssum;
            #pragma unroll
            for (int k = 0; k < MAX_ADJ; ++k)
                s_lp[buf][r][n * MAX_ADJ + k] = l[k] * inv;
        }
    };

    // Prologue: chunk 0 computed + softmaxed.
    compute_chunk(0);
    __syncthreads();
    softmax_chunk(0);
    __syncthreads();

    for (int c = 0; c < NCHUNK; ++c) {
        const int buf = c & 1;

        // Store chunk c: i-outer so each s_map value is read once and feeds
        // 4 row-stores. Plain coalesced dword stores (proven exact-byte).
        {
            const size_t rbase = b0 + (size_t)c * CHUNK;
            #pragma unroll
            for (int i = 0; i < NPOS; ++i) {
                const int p = tid + i * BLOCK;
                if (p < ROW_DW) {
                    const short t = s_map[p];
                    #pragma unroll
                    for (int r = 0; r < CHUNK; ++r) {
                        float v = 0.0f;
                        if (t >= 0) v = s_lp[buf][r][t];
                        out[(rbase + r) * (size_t)ROW_DW + p] = v;
                    }
                }
            }
        }

        // Compute next chunk into the other buffer; its FMA stream runs while
        // this chunk's posted stores drain (barrier vmcnt(0) comes after).
        if (c + 1 < NCHUNK) {
            compute_chunk(c + 1);
            __syncthreads();      // next logits visible; stores of c complete
            softmax_chunk(c + 1);
            __syncthreads();      // next probs ready
        }
    }
}

extern "C" void kernel_launch(void* const* d_in, const int* in_sizes, int n_in,
                              void* d_out, int out_size, void* d_ws, size_t ws_size,
                              hipStream_t stream) {
    const float* obs  = (const float*)d_in[0];
    const float* W    = (const float*)d_in[1];
    const float* bias = (const float*)d_in[2];
    const int*   idx  = (const int*)d_in[3];
    const float* mask = (const float*)d_in[4];
    float* out = (float*)d_out;

    const int B = in_sizes[0] / OBS_DIM;   // 32768, divisible by ROWS
    taxi_actor_kernel<<<B / ROWS, BLOCK, 0, stream>>>(obs, W, bias, idx, mask, out);
}